// Round 3
// baseline (382.196 us; speedup 1.0000x reference)
//
#include <hip/hip_runtime.h>

// Problem constants
#define B_  16
#define S_  1024
#define IN_ 1024
#define H_  1024
#define N1  (2*H_)          // 2048 output cols of GEMM1
#define M1  (B_*S_)         // 16384 rows of GEMM1
#define K1  IN_             // 1024
#define XN  (M1*IN_)        // 16,777,216 elems of x
#define WN  (N1*IN_)        //  2,097,152 elems of W

// Tiling
#define BM  128
#define BN  128
#define BK  64              // bf16 elems; row = 128 B = 8 chunks of 16 B (XOR-8 swizzled)
#define CP  130             // epilogue LDS col stride: transposed reads hit consecutive banks

typedef __attribute__((ext_vector_type(8))) short  short8;   // 8 bf16 = 4 VGPRs (MFMA A/B frag)
typedef __attribute__((ext_vector_type(4))) float  floatx4;  // MFMA C/D frag

// fp32 -> bf16 round-to-nearest-even
__device__ __forceinline__ unsigned short f2bf(float f) {
    unsigned int u = __float_as_uint(f);
    u += 0x7fffu + ((u >> 16) & 1u);
    return (unsigned short)(u >> 16);
}

// async global->LDS, 16 B per lane; LDS dst is wave-uniform base + lane*16
#define GLDS16(gp, lp) __builtin_amdgcn_global_load_lds(                      \
    (const __attribute__((address_space(1))) void*)(gp),                      \
    (__attribute__((address_space(3))) void*)(lp), 16, 0, 0)

// ---------------------------------------------------------------------------
// convert: fp32 -> bf16 for x and W (memory-bound). Block-uniform branch:
// XN is an exact multiple of 2048 (= elems per block).
// ---------------------------------------------------------------------------
__global__ __launch_bounds__(256) void convert_kernel(
    const float* __restrict__ x, const float* __restrict__ W,
    unsigned short* __restrict__ xb, unsigned short* __restrict__ Wb)
{
    size_t i = ((size_t)blockIdx.x * 256 + threadIdx.x) * 8;
    const float* src;
    unsigned short* dst;
    if (i < (size_t)XN) { src = x + i; dst = xb + i; }
    else                { src = W + (i - XN); dst = Wb + (i - XN); }
    float4 a = *(const float4*)(src);
    float4 b = *(const float4*)(src + 4);
    ushort4 p = { f2bf(a.x), f2bf(a.y), f2bf(a.z), f2bf(a.w) };
    ushort4 q = { f2bf(b.x), f2bf(b.y), f2bf(b.z), f2bf(b.w) };
    *(ushort4*)(dst)     = p;
    *(ushort4*)(dst + 4) = q;
}

// ---------------------------------------------------------------------------
// Shared K-loop shape (both GEMMs): 128x128 tile, BK=64, global_load_lds w16.
// LDS layout: [row][64] bf16, row stride 128 B = 8 chunks; chunk slot c holds
// global chunk c ^ (row&7). Frag read for k-chunk g at row r un-swizzles with
// g ^ (r&7): each 16-lane group covers all 8 chunk positions twice -> 2-way
// banks (free, m136). Global writes stay contiguous-128B-per-row coalesced.
// 32 MFMA per barrier (AITER-like), half the vmcnt(0) barrier drains of BK=32.
// ---------------------------------------------------------------------------

// GEMM1: C[m,n] = sum_k xb[m,k] * Wb[n,k]; epilogue relu -> fp32 keys/vals
// to d_out + bf16 transposed keysT/valsT to ws.
__global__ __launch_bounds__(256) void gemm1_kernel(
    const unsigned short* __restrict__ xb, const unsigned short* __restrict__ Wb,
    float* __restrict__ out,
    unsigned short* __restrict__ kT, unsigned short* __restrict__ vT)
{
    __shared__ unsigned short lds[BM * CP];          // 33,280 B; staging uses first 32 KB
    unsigned short* ldsA = lds;                      // [128][64] bf16
    unsigned short* ldsB = lds + BM * BK;            // [128][64]

    const int tid  = threadIdx.x;
    const int wave = tid >> 6, lane = tid & 63;
    const int quad = lane >> 4, r = lane & 15;
    const int wm = (wave >> 1) * 64;
    const int wn = (wave & 1) * 64;
    const int m0 = blockIdx.y * BM;
    const int n0 = blockIdx.x * BN;

    const unsigned short* Ag = xb + (size_t)m0 * K1;
    const unsigned short* Bg = Wb + (size_t)n0 * K1;

    floatx4 acc[4][4] = {};

    for (int kt = 0; kt < K1; kt += BK) {
        __syncthreads();
#pragma unroll
        for (int t = 0; t < 4; ++t) {
            int seg  = t * 4 + wave;                 // wave-uniform
            int slot = seg * 64 + lane;
            int row  = slot >> 3, c = slot & 7;
            int cs   = c ^ (row & 7);
            GLDS16(Ag + (size_t)row * K1 + kt + cs * 8, ldsA + seg * 512);
            GLDS16(Bg + (size_t)row * K1 + kt + cs * 8, ldsB + seg * 512);
        }
        __syncthreads();

#pragma unroll
        for (int s = 0; s < 2; ++s) {
            short8 af[4], bfr[4];
            const int g = s * 4 + quad;              // k-chunk index in [0,8)
#pragma unroll
            for (int i = 0; i < 4; ++i)
                af[i]  = *(const short8*)(ldsA + (wm + i * 16 + r) * BK + (g ^ (r & 7)) * 8);
#pragma unroll
            for (int j = 0; j < 4; ++j)
                bfr[j] = *(const short8*)(ldsB + (wn + j * 16 + r) * BK + (g ^ (r & 7)) * 8);
#pragma unroll
            for (int i = 0; i < 4; ++i)
#pragma unroll
                for (int j = 0; j < 4; ++j)
                    acc[i][j] = __builtin_amdgcn_mfma_f32_16x16x32_bf16(af[i], bfr[j], acc[i][j], 0, 0, 0);
        }
    }

    // ---------------- epilogue ----------------
    __syncthreads();                                  // staging LDS now dead; reuse as ldsC
    unsigned short* ldsC = lds;                       // [BM][CP] bf16 post-relu

    const bool isKeys = (blockIdx.x < 8);
    float* outKV    = out + (isKeys ? (size_t)M1 * H_ : (size_t)2 * M1 * H_);
    const int ncol0 = isKeys ? n0 : (n0 - 1024);

#pragma unroll
    for (int i = 0; i < 4; ++i)
#pragma unroll
        for (int j = 0; j < 4; ++j)
#pragma unroll
            for (int d = 0; d < 4; ++d) {
                int row_l = wm + i * 16 + quad * 4 + d;
                int col_l = wn + j * 16 + r;
                float v = fmaxf(acc[i][j][d], 0.0f);
                outKV[(size_t)(m0 + row_l) * H_ + ncol0 + col_l] = v;
                ldsC[row_l * CP + col_l] = f2bf(v);
            }
    __syncthreads();

    unsigned short* wsT = isKeys ? kT : vT;
    const int b  = m0 >> 10;
    const int s0 = m0 & 1023;
    unsigned short* dstBase = wsT + (size_t)b * H_ * S_ + (size_t)ncol0 * S_ + s0;
#pragma unroll
    for (int stp = 0; stp < 64; ++stp) {
        int o   = stp * 256 + tid;
        int n_l = o >> 7, m_l = o & 127;              // consecutive tid -> consecutive s (coalesced)
        dstBase[(size_t)n_l * S_ + m_l] = ldsC[m_l * CP + n_l];   // bank stride 1 on reads
    }
}

// GEMM2 (batched): mem[b][m,n] = sum_t keysT[b][m,t] * valsT[b][n,t]
__global__ __launch_bounds__(256) void gemm2_kernel(
    const unsigned short* __restrict__ kT, const unsigned short* __restrict__ vT,
    float* __restrict__ mem)
{
    __shared__ unsigned short lds[BM * BK * 2];      // 32,768 B -> 5 blocks/CU
    unsigned short* ldsA = lds;
    unsigned short* ldsB = lds + BM * BK;

    const int tid  = threadIdx.x;
    const int wave = tid >> 6, lane = tid & 63;
    const int quad = lane >> 4, r = lane & 15;
    const int wm = (wave >> 1) * 64;
    const int wn = (wave & 1) * 64;
    const int m0 = blockIdx.y * BM;
    const int n0 = blockIdx.x * BN;
    const int b  = blockIdx.z;

    const unsigned short* Ag = kT + (size_t)b * H_ * S_ + (size_t)m0 * S_;
    const unsigned short* Bg = vT + (size_t)b * H_ * S_ + (size_t)n0 * S_;

    floatx4 acc[4][4] = {};

    for (int kt = 0; kt < S_; kt += BK) {
        __syncthreads();
#pragma unroll
        for (int t = 0; t < 4; ++t) {
            int seg  = t * 4 + wave;
            int slot = seg * 64 + lane;
            int row  = slot >> 3, c = slot & 7;
            int cs   = c ^ (row & 7);
            GLDS16(Ag + (size_t)row * S_ + kt + cs * 8, ldsA + seg * 512);
            GLDS16(Bg + (size_t)row * S_ + kt + cs * 8, ldsB + seg * 512);
        }
        __syncthreads();

#pragma unroll
        for (int s = 0; s < 2; ++s) {
            short8 af[4], bfr[4];
            const int g = s * 4 + quad;
#pragma unroll
            for (int i = 0; i < 4; ++i)
                af[i]  = *(const short8*)(ldsA + (wm + i * 16 + r) * BK + (g ^ (r & 7)) * 8);
#pragma unroll
            for (int j = 0; j < 4; ++j)
                bfr[j] = *(const short8*)(ldsB + (wn + j * 16 + r) * BK + (g ^ (r & 7)) * 8);
#pragma unroll
            for (int i = 0; i < 4; ++i)
#pragma unroll
                for (int j = 0; j < 4; ++j)
                    acc[i][j] = __builtin_amdgcn_mfma_f32_16x16x32_bf16(af[i], bfr[j], acc[i][j], 0, 0, 0);
        }
    }

    float* outb = mem + (size_t)b * H_ * H_;
#pragma unroll
    for (int i = 0; i < 4; ++i)
#pragma unroll
        for (int j = 0; j < 4; ++j)
#pragma unroll
            for (int d = 0; d < 4; ++d) {
                int row_l = wm + i * 16 + quad * 4 + d;
                int col_l = wn + j * 16 + r;
                outb[(size_t)(m0 + row_l) * H_ + n0 + col_l] = acc[i][j][d];
            }
}

extern "C" void kernel_launch(void* const* d_in, const int* in_sizes, int n_in,
                              void* d_out, int out_size, void* d_ws, size_t ws_size,
                              hipStream_t stream) {
    const float* x = (const float*)d_in[0];   // [16,1024,1024] f32
    const float* W = (const float*)d_in[1];   // [2048,1024] f32
    float* out = (float*)d_out;               // mem(16M) | keys(16M) | vals(16M) f32

    // Stash bf16 inputs in d_out's mem region (64 MB; not written until gemm2)
    unsigned short* xb = (unsigned short*)d_out;            // 33.5 MB
    unsigned short* Wb = xb + (size_t)XN;                   //  4.2 MB (total 37.7 < 64 MB)

    // ws: keysT/valsT bf16 [B][H][S] (64 MB)
    unsigned short* kT = (unsigned short*)d_ws;
    unsigned short* vT = kT + (size_t)B_ * H_ * S_;

    convert_kernel<<<dim3((XN + WN) / 2048), dim3(256), 0, stream>>>(x, W, xb, Wb);

    dim3 g1(N1 / BN, M1 / BM);                // (16, 128)
    gemm1_kernel<<<g1, dim3(256), 0, stream>>>(xb, Wb, out, kT, vT);

    dim3 g2(H_ / BN, H_ / BM, B_);            // (8, 8, 16)
    gemm2_kernel<<<g2, dim3(256), 0, stream>>>(kT, vT, out);
}

// Round 4
// 365.103 us; speedup vs baseline: 1.0468x; 1.0468x over previous
//
#include <hip/hip_runtime.h>

// Problem constants
#define B_  16
#define S_  1024
#define IN_ 1024
#define H_  1024
#define N1  (2*H_)          // 2048 output cols of GEMM1
#define M1  (B_*S_)         // 16384 rows of GEMM1
#define K1  IN_             // 1024
#define XN  (M1*IN_)        // 16,777,216 elems of x
#define WN  (N1*IN_)        //  2,097,152 elems of W

// Tiling
#define BM  128
#define BN  128
#define BK  64              // bf16 elems; row = 128 B = 8 chunks of 16 B (XOR-8 swizzled)
#define CP  130             // epilogue LDS col stride: transposed reads hit consecutive banks

typedef __attribute__((ext_vector_type(8))) short  short8;   // 8 bf16 = 4 VGPRs (MFMA A/B frag)
typedef __attribute__((ext_vector_type(4))) float  floatx4;  // MFMA C/D frag

// fp32 -> bf16 round-to-nearest-even
__device__ __forceinline__ unsigned short f2bf(float f) {
    unsigned int u = __float_as_uint(f);
    u += 0x7fffu + ((u >> 16) & 1u);
    return (unsigned short)(u >> 16);
}

// async global->LDS, 16 B per lane; LDS dst is wave-uniform base + lane*16
#define GLDS16(gp, lp) __builtin_amdgcn_global_load_lds(                      \
    (const __attribute__((address_space(1))) void*)(gp),                      \
    (__attribute__((address_space(3))) void*)(lp), 16, 0, 0)

// ---------------------------------------------------------------------------
// convert: fp32 -> bf16 for x and W (memory-bound).
// ---------------------------------------------------------------------------
__global__ __launch_bounds__(256) void convert_kernel(
    const float* __restrict__ x, const float* __restrict__ W,
    unsigned short* __restrict__ xb, unsigned short* __restrict__ Wb)
{
    size_t i = ((size_t)blockIdx.x * 256 + threadIdx.x) * 8;
    const float* src;
    unsigned short* dst;
    if (i < (size_t)XN) { src = x + i; dst = xb + i; }
    else                { src = W + (i - XN); dst = Wb + (i - XN); }
    float4 a = *(const float4*)(src);
    float4 b = *(const float4*)(src + 4);
    ushort4 p = { f2bf(a.x), f2bf(a.y), f2bf(a.z), f2bf(a.w) };
    ushort4 q = { f2bf(b.x), f2bf(b.y), f2bf(b.z), f2bf(b.w) };
    *(ushort4*)(dst)     = p;
    *(ushort4*)(dst + 4) = q;
}

// ---------------------------------------------------------------------------
// K-loop shape (both GEMMs): 128x128 tile, BK=64, global_load_lds w16,
// XOR-8 chunk swizzle (2-way banks = free). NEW this round: 1D grids with
// XCD-aware decode (xcd ~ linear%8, round-robin dispatch heuristic) so blocks
// co-resident on one XCD share a <=4MB operand working set that fits its L2.
// ---------------------------------------------------------------------------

// GEMM1: C[m,n] = sum_k xb[m,k] * Wb[n,k]; epilogue relu -> fp32 keys/vals
// to d_out + bf16 transposed keysT/valsT to ws.
// Decode: each XCD processes 8x8-tile rectangles (A 2MB + B 2MB = 4MB in L2).
__global__ __launch_bounds__(256) void gemm1_kernel(
    const unsigned short* __restrict__ xb, const unsigned short* __restrict__ Wb,
    float* __restrict__ out,
    unsigned short* __restrict__ kT, unsigned short* __restrict__ vT)
{
    __shared__ unsigned short lds[BM * CP];          // 33,280 B; staging uses first 32 KB
    unsigned short* ldsA = lds;                      // [128][64] bf16
    unsigned short* ldsB = lds + BM * BK;            // [128][64]

    const int tid  = threadIdx.x;
    const int wave = tid >> 6, lane = tid & 63;
    const int quad = lane >> 4, r = lane & 15;
    const int wm = (wave >> 1) * 64;
    const int wn = (wave & 1) * 64;

    // XCD-grouped rectangle decode: 2048 blocks = 32 rects of 8m x 8n tiles.
    const int L    = blockIdx.x;
    const int xcd  = L & 7;
    const int s    = L >> 3;                         // 0..255 (per-XCD sequence)
    const int rect = (s >> 6) * 8 + xcd;             // 0..31; 4 rects per XCD, sequential
    const int idx  = s & 63;
    const int rm   = rect & 15, rc = rect >> 4;      // rect grid: 16 rows x 2 cols
    const int mt   = rm * 8 + (idx >> 3);            // m-tile 0..127
    const int nt   = rc * 8 + (idx & 7);             // n-tile 0..15
    const int m0   = mt * BM;
    const int n0   = nt * BN;

    const unsigned short* Ag = xb + (size_t)m0 * K1;
    const unsigned short* Bg = Wb + (size_t)n0 * K1;

    floatx4 acc[4][4] = {};

    for (int kt = 0; kt < K1; kt += BK) {
        __syncthreads();
#pragma unroll
        for (int t = 0; t < 4; ++t) {
            int seg  = t * 4 + wave;                 // wave-uniform
            int slot = seg * 64 + lane;
            int row  = slot >> 3, c = slot & 7;
            int cs   = c ^ (row & 7);
            GLDS16(Ag + (size_t)row * K1 + kt + cs * 8, ldsA + seg * 512);
            GLDS16(Bg + (size_t)row * K1 + kt + cs * 8, ldsB + seg * 512);
        }
        __syncthreads();

#pragma unroll
        for (int sc = 0; sc < 2; ++sc) {
            short8 af[4], bfr[4];
            const int g = sc * 4 + quad;             // k-chunk index in [0,8)
#pragma unroll
            for (int i = 0; i < 4; ++i)
                af[i]  = *(const short8*)(ldsA + (wm + i * 16 + r) * BK + (g ^ (r & 7)) * 8);
#pragma unroll
            for (int j = 0; j < 4; ++j)
                bfr[j] = *(const short8*)(ldsB + (wn + j * 16 + r) * BK + (g ^ (r & 7)) * 8);
#pragma unroll
            for (int i = 0; i < 4; ++i)
#pragma unroll
                for (int j = 0; j < 4; ++j)
                    acc[i][j] = __builtin_amdgcn_mfma_f32_16x16x32_bf16(af[i], bfr[j], acc[i][j], 0, 0, 0);
        }
    }

    // ---------------- epilogue ----------------
    __syncthreads();                                  // staging LDS now dead; reuse as ldsC
    unsigned short* ldsC = lds;                       // [BM][CP] bf16 post-relu

    const bool isKeys = (nt < 8);
    float* outKV    = out + (isKeys ? (size_t)M1 * H_ : (size_t)2 * M1 * H_);
    const int ncol0 = isKeys ? n0 : (n0 - 1024);

#pragma unroll
    for (int i = 0; i < 4; ++i)
#pragma unroll
        for (int j = 0; j < 4; ++j)
#pragma unroll
            for (int d = 0; d < 4; ++d) {
                int row_l = wm + i * 16 + quad * 4 + d;
                int col_l = wn + j * 16 + r;
                float v = fmaxf(acc[i][j][d], 0.0f);
                outKV[(size_t)(m0 + row_l) * H_ + ncol0 + col_l] = v;
                ldsC[row_l * CP + col_l] = f2bf(v);
            }
    __syncthreads();

    unsigned short* wsT = isKeys ? kT : vT;
    const int b  = m0 >> 10;
    const int s0 = m0 & 1023;
    unsigned short* dstBase = wsT + (size_t)b * H_ * S_ + (size_t)ncol0 * S_ + s0;
#pragma unroll
    for (int stp = 0; stp < 64; ++stp) {
        int o   = stp * 256 + tid;
        int n_l = o >> 7, m_l = o & 127;              // consecutive tid -> consecutive s (coalesced)
        dstBase[(size_t)n_l * S_ + m_l] = ldsC[m_l * CP + n_l];   // bank stride 1 on reads
    }
}

// GEMM2 (batched): mem[b][m,n] = sum_t keysT[b][m,t] * valsT[b][n,t]
// Decode: each XCD owns 2 whole batches sequentially (4MB/batch fits its L2).
__global__ __launch_bounds__(256) void gemm2_kernel(
    const unsigned short* __restrict__ kT, const unsigned short* __restrict__ vT,
    float* __restrict__ mem)
{
    __shared__ unsigned short lds[BM * BK * 2];      // 32,768 B
    unsigned short* ldsA = lds;
    unsigned short* ldsB = lds + BM * BK;

    const int tid  = threadIdx.x;
    const int wave = tid >> 6, lane = tid & 63;
    const int quad = lane >> 4, r = lane & 15;
    const int wm = (wave >> 1) * 64;
    const int wn = (wave & 1) * 64;

    const int L   = blockIdx.x;
    const int xcd = L & 7;
    const int s   = L >> 3;                          // 0..127
    const int b   = xcd * 2 + (s >> 6);              // batch; 2 per XCD, sequential
    const int t   = s & 63;
    const int m0  = (t >> 3) * BM;
    const int n0  = (t & 7) * BN;

    const unsigned short* Ag = kT + (size_t)b * H_ * S_ + (size_t)m0 * S_;
    const unsigned short* Bg = vT + (size_t)b * H_ * S_ + (size_t)n0 * S_;

    floatx4 acc[4][4] = {};

    for (int kt = 0; kt < S_; kt += BK) {
        __syncthreads();
#pragma unroll
        for (int tt = 0; tt < 4; ++tt) {
            int seg  = tt * 4 + wave;
            int slot = seg * 64 + lane;
            int row  = slot >> 3, c = slot & 7;
            int cs   = c ^ (row & 7);
            GLDS16(Ag + (size_t)row * S_ + kt + cs * 8, ldsA + seg * 512);
            GLDS16(Bg + (size_t)row * S_ + kt + cs * 8, ldsB + seg * 512);
        }
        __syncthreads();

#pragma unroll
        for (int sc = 0; sc < 2; ++sc) {
            short8 af[4], bfr[4];
            const int g = sc * 4 + quad;
#pragma unroll
            for (int i = 0; i < 4; ++i)
                af[i]  = *(const short8*)(ldsA + (wm + i * 16 + r) * BK + (g ^ (r & 7)) * 8);
#pragma unroll
            for (int j = 0; j < 4; ++j)
                bfr[j] = *(const short8*)(ldsB + (wn + j * 16 + r) * BK + (g ^ (r & 7)) * 8);
#pragma unroll
            for (int i = 0; i < 4; ++i)
#pragma unroll
                for (int j = 0; j < 4; ++j)
                    acc[i][j] = __builtin_amdgcn_mfma_f32_16x16x32_bf16(af[i], bfr[j], acc[i][j], 0, 0, 0);
        }
    }

    float* outb = mem + (size_t)b * H_ * H_;
#pragma unroll
    for (int i = 0; i < 4; ++i)
#pragma unroll
        for (int j = 0; j < 4; ++j)
#pragma unroll
            for (int d = 0; d < 4; ++d) {
                int row_l = wm + i * 16 + quad * 4 + d;
                int col_l = wn + j * 16 + r;
                outb[(size_t)(m0 + row_l) * H_ + n0 + col_l] = acc[i][j][d];
            }
}

extern "C" void kernel_launch(void* const* d_in, const int* in_sizes, int n_in,
                              void* d_out, int out_size, void* d_ws, size_t ws_size,
                              hipStream_t stream) {
    const float* x = (const float*)d_in[0];   // [16,1024,1024] f32
    const float* W = (const float*)d_in[1];   // [2048,1024] f32
    float* out = (float*)d_out;               // mem(16M) | keys(16M) | vals(16M) f32

    // Stash bf16 inputs in d_out's mem region (64 MB; not written until gemm2)
    unsigned short* xb = (unsigned short*)d_out;            // 33.5 MB
    unsigned short* Wb = xb + (size_t)XN;                   //  4.2 MB (total 37.7 < 64 MB)

    // ws: keysT/valsT bf16 [B][H][S] (64 MB)
    unsigned short* kT = (unsigned short*)d_ws;
    unsigned short* vT = kT + (size_t)B_ * H_ * S_;

    convert_kernel<<<dim3((XN + WN) / 2048), dim3(256), 0, stream>>>(x, W, xb, Wb);

    gemm1_kernel<<<dim3(2048), dim3(256), 0, stream>>>(xb, Wb, out, kT, vT);

    gemm2_kernel<<<dim3(1024), dim3(256), 0, stream>>>(kT, vT, out);
}